// Round 7
// baseline (478.833 us; speedup 1.0000x reference)
//
#include <hip/hip_runtime.h>
#include <math.h>

// Problem constants (fixed by reference setup_inputs)
constexpr int B = 2, C = 16, H = 160, W = 192, S = 3, D = 48;
constexpr int HW = H * W;
constexpr int NPIX = B * HW;                 // 61440
// workspace layout (f64): ka01 [S][NPIX] double2 | ka2 [S][NPIX] | kt [S*3*B]
constexpr size_t KA01_ELEMS = (size_t)S * NPIX * 2;
constexpr size_t KA2_ELEMS  = (size_t)S * NPIX;
constexpr size_t KT_ELEMS   = (size_t)S * 3 * B;
constexpr size_t WS_NEEDED  = (KA01_ELEMS + KA2_ELEMS + KT_ELEMS) * sizeof(double);

typedef float  f32x2 __attribute__((ext_vector_type(2)));
typedef double f64x2 __attribute__((ext_vector_type(2)));

__device__ __forceinline__ f32x2 load2(const float* p) {
    f32x2 v;
    __builtin_memcpy(&v, p, sizeof(f32x2));  // align-4 safe
    return v;
}

// ---------------------------------------------------------------------------
// Kernel 1: depth-invariant geometry.
//   ka = Ks*R*K^-1*pix  (per pixel, per view; f64)   kt = Ks*t  (per view, b)
// ---------------------------------------------------------------------------
__global__ __launch_bounds__(256) void geom_kernel(
    const float* __restrict__ ref_intr,    // [B,3,3]
    const float* __restrict__ src_intr,    // [S,B,3,3]
    const float* __restrict__ ref_to_src,  // [S,B,4,4]
    f64x2* __restrict__ ka01,              // [S][NPIX]
    double* __restrict__ ka2,              // [S][NPIX]
    double* __restrict__ kt)               // [S][3][B]
{
    const int pi = blockIdx.x * blockDim.x + threadIdx.x;
    if (pi >= NPIX) return;
    const int w = pi % W;
    const int h = (pi / W) % H;
    const int b = pi / HW;

    // f64 3x3 inverse of ref intrinsics (adjugate)
    const float* Kp = ref_intr + b * 9;
    const double a00 = Kp[0], a01 = Kp[1], a02 = Kp[2];
    const double a10 = Kp[3], a11 = Kp[4], a12 = Kp[5];
    const double a20 = Kp[6], a21 = Kp[7], a22 = Kp[8];
    const double cof00 =  (a11 * a22 - a12 * a21);
    const double cof01 = -(a10 * a22 - a12 * a20);
    const double cof02 =  (a10 * a21 - a11 * a20);
    const double cof10 = -(a01 * a22 - a02 * a21);
    const double cof11 =  (a00 * a22 - a02 * a20);
    const double cof12 = -(a00 * a21 - a01 * a20);
    const double cof20 =  (a01 * a12 - a02 * a11);
    const double cof21 = -(a00 * a12 - a02 * a10);
    const double cof22 =  (a00 * a11 - a01 * a10);
    const double det = a00 * cof00 + a01 * cof01 + a02 * cof02;
    const double invdet = 1.0 / det;
    const double i00 = cof00 * invdet, i01 = cof10 * invdet, i02 = cof20 * invdet;
    const double i10 = cof01 * invdet, i11 = cof11 * invdet, i12 = cof21 * invdet;
    const double i20 = cof02 * invdet, i21 = cof12 * invdet, i22 = cof22 * invdet;

    const double u = (double)w;
    const double v = (double)h;
    const double rayx = i00 * u + i01 * v + i02;
    const double rayy = i10 * u + i11 * v + i12;
    const double rayz = i20 * u + i21 * v + i22;

    #pragma unroll
    for (int s = 0; s < S; ++s) {
        const float* Tp  = ref_to_src + (s * B + b) * 16;
        const float* Ksp = src_intr   + (s * B + b) * 9;
        const double ar0 = (double)Tp[0] * rayx + (double)Tp[1] * rayy + (double)Tp[2]  * rayz;
        const double ar1 = (double)Tp[4] * rayx + (double)Tp[5] * rayy + (double)Tp[6]  * rayz;
        const double ar2 = (double)Tp[8] * rayx + (double)Tp[9] * rayy + (double)Tp[10] * rayz;
        f64x2 k01;
        k01.x = (double)Ksp[0] * ar0 + (double)Ksp[1] * ar1 + (double)Ksp[2] * ar2;
        k01.y = (double)Ksp[3] * ar0 + (double)Ksp[4] * ar1 + (double)Ksp[5] * ar2;
        ka01[(size_t)s * NPIX + pi] = k01;
        ka2[(size_t)s * NPIX + pi] = (double)Ksp[6] * ar0 + (double)Ksp[7] * ar1 + (double)Ksp[8] * ar2;
        if (pi < B) {   // one thread per b writes kt
            const int bb = pi;
            const float* Tp2  = ref_to_src + (s * B + bb) * 16;
            const float* Ksp2 = src_intr   + (s * B + bb) * 9;
            const double t0 = Tp2[3], t1 = Tp2[7], t2 = Tp2[11];
            kt[(s * 3 + 0) * B + bb] = (double)Ksp2[0] * t0 + (double)Ksp2[1] * t1 + (double)Ksp2[2] * t2;
            kt[(s * 3 + 1) * B + bb] = (double)Ksp2[3] * t0 + (double)Ksp2[4] * t1 + (double)Ksp2[5] * t2;
            kt[(s * 3 + 2) * B + bb] = (double)Ksp2[6] * t0 + (double)Ksp2[7] * t1 + (double)Ksp2[8] * t2;
        }
    }
}

// ---------------------------------------------------------------------------
// Kernel 2: one thread per output element (w fastest; d,b uniform per block).
// __launch_bounds__(256,8): cap VGPR at 64 for 8 waves/SIMD — round-6 at 80
// VGPR / 6 waves was latency-bound (VALUBusy 44%).
// ---------------------------------------------------------------------------
__global__ __launch_bounds__(256, 8) void sweep_kernel(
    const float* __restrict__ ref_feats,   // [B,C,H,W]
    const float* __restrict__ src_feats,   // [S,B,C,H,W]
    const f64x2* __restrict__ ka01,        // [S][NPIX]
    const double* __restrict__ ka2,        // [S][NPIX]
    const double* __restrict__ kt,         // [S][3][B]
    const float* __restrict__ depths,      // [D]
    float* __restrict__ out)               // [B,D,H,W]
{
    const int idx = blockIdx.x * blockDim.x + threadIdx.x;
    const int total = B * D * HW;
    if (idx >= total) return;

    const int w = idx % W;
    const int h = (idx / W) % H;
    const int d = (idx / HW) % D;   // uniform within block
    const int b = idx / (HW * D);   // uniform within block
    const int pi = b * HW + h * W + w;

    const double depth = (double)depths[d];

    // ref fragment: load + zero-mean + norm (f32)
    float f1[C];
    const float* rp = ref_feats + (b * C) * HW + h * W + w;
    float sum1 = 0.0f;
    #pragma unroll
    for (int c = 0; c < C; ++c) {
        f1[c] = rp[c * HW];
        sum1 += f1[c];
    }
    const float m1 = sum1 * (1.0f / C);
    float sq1 = 0.0f;
    float sumf1p = 0.0f;   // residual sum of zero-meaned f1 (~1e-6, used to de-bias dot)
    #pragma unroll
    for (int c = 0; c < C; ++c) {
        f1[c] -= m1;
        sq1 = fmaf(f1[c], f1[c], sq1);
        sumf1p += f1[c];
    }
    const float n1 = sqrtf(sq1);

    float cost = 0.0f;

    #pragma unroll
    for (int s = 0; s < S; ++s) {
        // p = depth*ka + kt   (f64; geometry must stay f64 — NCC amplifies
        // x,y error by ~2/n2 with n2 as small as ~7e-4)
        const f64x2 kv = ka01[(size_t)s * NPIX + pi];
        const double k2v = ka2[(size_t)s * NPIX + pi];
        const double p0 = depth * kv.x + kt[(s * 3 + 0) * B + b];
        const double p1 = depth * kv.y + kt[(s * 3 + 1) * B + b];
        const double p2 = depth * k2v  + kt[(s * 3 + 2) * B + b];

        const bool valid = p2 > 0.001;
        const double zs = fmax(p2, 0.001);
        const double invz = 1.0 / zs;
        const double x = p0 * invz;
        const double y = p1 * invz;

        const double x0f = floor(x);
        const double y0f = floor(y);
        const float fx = (float)(x - x0f);
        const float fy = (float)(y - y0f);
        const int x0 = (int)x0f;
        const int y0 = (int)y0f;
        const int y1 = y0 + 1;

        // x-pair weights: one 8B load at xa=clamp(x0,0,W-2); weights select
        // so wA*A + wB*B == w_x0*p[x0c] + w_x1*p[x1c] with OOB taps zeroed.
        const bool interior = (x0 >= 0) && (x0 < W - 1);
        const float wA = interior ? (1.0f - fx) : ((x0 == -1)    ? fx          : 0.0f);
        const float wB = interior ? fx          : ((x0 == W - 1) ? (1.0f - fx) : 0.0f);

        const bool oky0 = (y0 >= 0) && (y0 < H);
        const bool oky1 = (y1 >= 0) && (y1 < H);
        const float wy0 = (valid && oky0) ? (1.0f - fy) : 0.0f;
        const float wy1 = (valid && oky1) ? fy : 0.0f;

        // fold into 4 tap weights: bilinear = 4 FMA/channel
        const float w00 = wy0 * wA;
        const float w01 = wy0 * wB;
        const float w10 = wy1 * wA;
        const float w11 = wy1 * wB;

        const int xa  = min(max(x0, 0), W - 2);
        const int y0c = min(max(y0, 0), H - 1);
        const int y1c = min(max(y1, 0), H - 1);

        const float* base = src_feats + ((size_t)(s * B + b) * C) * HW;
        const float* pr0 = base + (y0c * W + xa);
        const float* pr1 = base + (y1c * W + xa);

        // pass 1: bilinear + sum + dot (dot = Σ f1'·f2; de-biased after)
        float f2[C];
        float sum2 = 0.0f;
        float dot = 0.0f;
        #pragma unroll
        for (int c = 0; c < C; ++c) {
            const f32x2 r0 = load2(pr0);
            const f32x2 r1 = load2(pr1);
            const float val = fmaf(w00, r0.x, fmaf(w01, r0.y, fmaf(w10, r1.x, w11 * r1.y)));
            f2[c] = val;
            sum2 += val;
            dot = fmaf(f1[c], val, dot);
            pr0 += HW;
            pr1 += HW;
        }
        // pass 2: stable variance (explicit mean subtraction — do NOT use
        // Σf2² − C·m2², catastrophic cancellation at low-variance pixels)
        const float m2 = sum2 * (1.0f / C);
        float sq2 = 0.0f;
        #pragma unroll
        for (int c = 0; c < C; ++c) {
            const float t = f2[c] - m2;
            sq2 = fmaf(t, t, sq2);
        }
        dot = fmaf(-m2, sumf1p, dot);
        const float den = n1 * sqrtf(sq2) + 1e-6f;
        cost += dot / den;
    }

    out[idx] = cost * (1.0f / S);
}

// ---------------------------------------------------------------------------
// Fallback: round-3-style monolithic kernel (used only if ws too small)
// ---------------------------------------------------------------------------
__global__ __launch_bounds__(256) void plane_sweep_fallback(
    const float* __restrict__ ref_feats, const float* __restrict__ src_feats,
    const float* __restrict__ ref_intr, const float* __restrict__ src_intr,
    const float* __restrict__ ref_to_src, const float* __restrict__ depths,
    float* __restrict__ out)
{
    const int idx = blockIdx.x * blockDim.x + threadIdx.x;
    const int total = B * D * HW;
    if (idx >= total) return;
    const int w = idx % W;
    const int h = (idx / W) % H;
    const int d = (idx / HW) % D;
    const int b = idx / (HW * D);

    const float* Kp = ref_intr + b * 9;
    const double a00 = Kp[0], a01 = Kp[1], a02 = Kp[2];
    const double a10 = Kp[3], a11 = Kp[4], a12 = Kp[5];
    const double a20 = Kp[6], a21 = Kp[7], a22 = Kp[8];
    const double cof00 =  (a11 * a22 - a12 * a21);
    const double cof01 = -(a10 * a22 - a12 * a20);
    const double cof02 =  (a10 * a21 - a11 * a20);
    const double cof10 = -(a01 * a22 - a02 * a21);
    const double cof11 =  (a00 * a22 - a02 * a20);
    const double cof12 = -(a00 * a21 - a01 * a20);
    const double cof20 =  (a01 * a12 - a02 * a11);
    const double cof21 = -(a00 * a12 - a02 * a10);
    const double cof22 =  (a00 * a11 - a01 * a10);
    const double det = a00 * cof00 + a01 * cof01 + a02 * cof02;
    const double invdet = 1.0 / det;
    const double i00 = cof00 * invdet, i01 = cof10 * invdet, i02 = cof20 * invdet;
    const double i10 = cof01 * invdet, i11 = cof11 * invdet, i12 = cof21 * invdet;
    const double i20 = cof02 * invdet, i21 = cof12 * invdet, i22 = cof22 * invdet;
    const double u = (double)w, v = (double)h;
    const double rayx = i00 * u + i01 * v + i02;
    const double rayy = i10 * u + i11 * v + i12;
    const double rayz = i20 * u + i21 * v + i22;
    const double depth = (double)depths[d];
    const double X0 = depth * rayx, X1 = depth * rayy, X2 = depth * rayz;

    float f1[C];
    const float* rp = ref_feats + (b * C) * HW + h * W + w;
    float sum1 = 0.0f;
    #pragma unroll
    for (int c = 0; c < C; ++c) { f1[c] = rp[c * HW]; sum1 += f1[c]; }
    const float m1 = sum1 * (1.0f / C);
    float sq1 = 0.0f;
    #pragma unroll
    for (int c = 0; c < C; ++c) { f1[c] -= m1; sq1 += f1[c] * f1[c]; }
    const float n1 = sqrtf(sq1);

    float cost = 0.0f;
    for (int s = 0; s < S; ++s) {
        const float* Tp  = ref_to_src + (s * B + b) * 16;
        const float* Ksp = src_intr   + (s * B + b) * 9;
        const double Xsx = (double)Tp[0] * X0 + (double)Tp[1] * X1 + (double)Tp[2]  * X2 + (double)Tp[3];
        const double Xsy = (double)Tp[4] * X0 + (double)Tp[5] * X1 + (double)Tp[6]  * X2 + (double)Tp[7];
        const double Xsz = (double)Tp[8] * X0 + (double)Tp[9] * X1 + (double)Tp[10] * X2 + (double)Tp[11];
        const double p0 = (double)Ksp[0] * Xsx + (double)Ksp[1] * Xsy + (double)Ksp[2] * Xsz;
        const double p1 = (double)Ksp[3] * Xsx + (double)Ksp[4] * Xsy + (double)Ksp[5] * Xsz;
        const double p2 = (double)Ksp[6] * Xsx + (double)Ksp[7] * Xsy + (double)Ksp[8] * Xsz;
        const bool valid = p2 > 0.001;
        const double zs = fmax(p2, 0.001);
        const double invz = 1.0 / zs;
        const double x = p0 * invz, y = p1 * invz;
        const double x0f = floor(x), y0f = floor(y);
        const float fx = (float)(x - x0f), fy = (float)(y - y0f);
        const int x0 = (int)x0f, y0 = (int)y0f, y1 = y0 + 1;
        const bool interior = (x0 >= 0) && (x0 < W - 1);
        const float wA = interior ? (1.0f - fx) : ((x0 == -1)    ? fx          : 0.0f);
        const float wB = interior ? fx          : ((x0 == W - 1) ? (1.0f - fx) : 0.0f);
        const bool oky0 = (y0 >= 0) && (y0 < H);
        const bool oky1 = (y1 >= 0) && (y1 < H);
        const float wy0 = (valid && oky0) ? (1.0f - fy) : 0.0f;
        const float wy1 = (valid && oky1) ? fy : 0.0f;
        const int xa  = min(max(x0, 0), W - 2);
        const int y0c = min(max(y0, 0), H - 1);
        const int y1c = min(max(y1, 0), H - 1);
        const int off0 = y0c * W + xa, off1 = y1c * W + xa;
        const float* base = src_feats + ((size_t)(s * B + b) * C) * HW;
        float f2[C];
        float sum2 = 0.0f;
        #pragma unroll
        for (int c = 0; c < C; ++c) {
            const float* pc = base + c * HW;
            const f32x2 r0 = load2(pc + off0);
            const f32x2 r1 = load2(pc + off1);
            const float t0v = fmaf(wA, r0.x, wB * r0.y);
            const float t1v = fmaf(wA, r1.x, wB * r1.y);
            const float val = fmaf(wy0, t0v, wy1 * t1v);
            f2[c] = val; sum2 += val;
        }
        const float m2 = sum2 * (1.0f / C);
        float sq2 = 0.0f, dot = 0.0f;
        #pragma unroll
        for (int c = 0; c < C; ++c) {
            const float f2c = f2[c] - m2;
            sq2 = fmaf(f2c, f2c, sq2);
            dot = fmaf(f1[c], f2c, dot);
        }
        cost += dot / (n1 * sqrtf(sq2) + 1e-6f);
    }
    out[idx] = cost * (1.0f / S);
}

extern "C" void kernel_launch(void* const* d_in, const int* in_sizes, int n_in,
                              void* d_out, int out_size, void* d_ws, size_t ws_size,
                              hipStream_t stream) {
    const float* ref_feats  = (const float*)d_in[0];
    const float* src_feats  = (const float*)d_in[1];
    const float* ref_intr   = (const float*)d_in[2];
    const float* src_intr   = (const float*)d_in[3];
    const float* ref_to_src = (const float*)d_in[4];
    const float* depths     = (const float*)d_in[5];
    float* out = (float*)d_out;
    const int total = B * D * H * W;

    if (ws_size >= WS_NEEDED) {
        f64x2*  ka01 = (f64x2*)d_ws;
        double* ka2  = (double*)d_ws + KA01_ELEMS;
        double* kt   = (double*)d_ws + KA01_ELEMS + KA2_ELEMS;
        geom_kernel<<<(NPIX + 255) / 256, 256, 0, stream>>>(
            ref_intr, src_intr, ref_to_src, ka01, ka2, kt);
        sweep_kernel<<<(total + 255) / 256, 256, 0, stream>>>(
            ref_feats, src_feats, ka01, ka2, kt, depths, out);
    } else {
        plane_sweep_fallback<<<(total + 255) / 256, 256, 0, stream>>>(
            ref_feats, src_feats, ref_intr, src_intr, ref_to_src, depths, out);
    }
}

// Round 8
// 222.311 us; speedup vs baseline: 2.1539x; 2.1539x over previous
//
#include <hip/hip_runtime.h>
#include <math.h>

// Problem constants (fixed by reference setup_inputs)
constexpr int B = 2, C = 16, H = 160, W = 192, S = 3, D = 48;
constexpr int HW = H * W;
constexpr int NP = S * B;                    // 6 (s,b) pairs
// ws layout (f64): P[NP][9] | kt[NP][3]  -> 72 doubles = 576 B
constexpr size_t WS_NEEDED = (size_t)(NP * 9 + NP * 3) * sizeof(double);

typedef float f32x2 __attribute__((ext_vector_type(2)));

__device__ __forceinline__ f32x2 load2(const float* p) {
    f32x2 v;
    __builtin_memcpy(&v, p, sizeof(f32x2));  // align-4 safe
    return v;
}

// ---------------------------------------------------------------------------
// Kernel 1 (1 block, 128 threads): P = Ks*R*K^-1 and kt = Ks*t per (s,b).
// 72 doubles total -> d_ws. All f64.
// ---------------------------------------------------------------------------
__global__ __launch_bounds__(128) void geom_small_kernel(
    const float* __restrict__ ref_intr,    // [B,3,3]
    const float* __restrict__ src_intr,    // [S,B,3,3]
    const float* __restrict__ ref_to_src,  // [S,B,4,4]
    double* __restrict__ gp)               // [NP*9 + NP*3]
{
    const int t = threadIdx.x;

    if (t < NP * 9) {
        const int pair = t / 9;            // s*B + b
        const int e    = t % 9;
        const int i    = e / 3;
        const int j    = e % 3;
        const int b    = pair % B;

        // f64 3x3 inverse of ref intrinsics (adjugate)
        const float* Kp = ref_intr + b * 9;
        const double a00 = Kp[0], a01 = Kp[1], a02 = Kp[2];
        const double a10 = Kp[3], a11 = Kp[4], a12 = Kp[5];
        const double a20 = Kp[6], a21 = Kp[7], a22 = Kp[8];
        const double cof00 =  (a11 * a22 - a12 * a21);
        const double cof01 = -(a10 * a22 - a12 * a20);
        const double cof02 =  (a10 * a21 - a11 * a20);
        const double cof10 = -(a01 * a22 - a02 * a21);
        const double cof11 =  (a00 * a22 - a02 * a20);
        const double cof12 = -(a00 * a21 - a01 * a20);
        const double cof20 =  (a01 * a12 - a02 * a11);
        const double cof21 = -(a00 * a12 - a02 * a10);
        const double cof22 =  (a00 * a11 - a01 * a10);
        const double det = a00 * cof00 + a01 * cof01 + a02 * cof02;
        const double invdet = 1.0 / det;
        // inv[r][c] = cof[c][r]/det
        double kinv[9];
        kinv[0] = cof00 * invdet; kinv[1] = cof10 * invdet; kinv[2] = cof20 * invdet;
        kinv[3] = cof01 * invdet; kinv[4] = cof11 * invdet; kinv[5] = cof21 * invdet;
        kinv[6] = cof02 * invdet; kinv[7] = cof12 * invdet; kinv[8] = cof22 * invdet;

        const float* Tp  = ref_to_src + pair * 16;   // R = Tp[m*4+k]
        const float* Ksp = src_intr   + pair * 9;

        // row i of Ks*R:  ksr[k] = sum_m Ks[i][m]*R[m][k]
        double ksr[3];
        #pragma unroll
        for (int k = 0; k < 3; ++k) {
            ksr[k] = (double)Ksp[i * 3 + 0] * (double)Tp[0 * 4 + k]
                   + (double)Ksp[i * 3 + 1] * (double)Tp[1 * 4 + k]
                   + (double)Ksp[i * 3 + 2] * (double)Tp[2 * 4 + k];
        }
        // P[i][j] = sum_k ksr[k] * kinv[k][j]
        gp[pair * 9 + e] = ksr[0] * kinv[0 * 3 + j]
                         + ksr[1] * kinv[1 * 3 + j]
                         + ksr[2] * kinv[2 * 3 + j];
    } else if (t < NP * 9 + NP * 3) {
        const int tt   = t - NP * 9;
        const int pair = tt / 3;
        const int i    = tt % 3;
        const float* Tp  = ref_to_src + pair * 16;
        const float* Ksp = src_intr   + pair * 9;
        gp[NP * 9 + pair * 3 + i] =
              (double)Ksp[i * 3 + 0] * (double)Tp[3]
            + (double)Ksp[i * 3 + 1] * (double)Tp[7]
            + (double)Ksp[i * 3 + 2] * (double)Tp[11];
    }
}

// ---------------------------------------------------------------------------
// Kernel 2: one thread per output element; w fastest, (b,d) block-uniform
// (derived from blockIdx only -> scalar loads of P/kt). Geometry per view:
// ka = P*(u,v,1) (6 f64 FMA) + p = depth*ka+kt (3 FMA) + 1 f64 rcp.
// ---------------------------------------------------------------------------
__global__ __launch_bounds__(256) void sweep_kernel(
    const float* __restrict__ ref_feats,   // [B,C,H,W]
    const float* __restrict__ src_feats,   // [S,B,C,H,W]
    const double* __restrict__ gp,         // P[NP][9] | kt[NP][3]
    const float* __restrict__ depths,      // [D]
    float* __restrict__ out)               // [B,D,H,W]
{
    const int block_base = blockIdx.x * 256;       // uniform
    const int d = (block_base / HW) % D;           // uniform (HW%256? 30720/256=120 -> exact)
    const int b = block_base / (HW * D);           // uniform
    const int idx = block_base + threadIdx.x;

    const int w = idx % W;
    const int h = (idx / W) % H;

    const double depth = (double)depths[d];        // uniform -> scalar
    const double u = (double)w;
    const double v = (double)h;

    // ref fragment: load + zero-mean + norm (f32)
    float f1[C];
    const float* rp = ref_feats + (b * C) * HW + h * W + w;
    float sum1 = 0.0f;
    #pragma unroll
    for (int c = 0; c < C; ++c) {
        f1[c] = *rp;
        sum1 += f1[c];
        rp += HW;
    }
    const float m1 = sum1 * (1.0f / C);
    float sq1 = 0.0f;
    float sumf1p = 0.0f;   // residual sum of zero-meaned f1 (de-biases fused dot)
    #pragma unroll
    for (int c = 0; c < C; ++c) {
        f1[c] -= m1;
        sq1 = fmaf(f1[c], f1[c], sq1);
        sumf1p += f1[c];
    }
    const float n1 = sqrtf(sq1);

    float cost = 0.0f;

    #pragma unroll 1
    for (int s = 0; s < S; ++s) {
        const int pair = s * B + b;                // uniform
        const double* Pp  = gp + pair * 9;
        const double* ktp = gp + NP * 9 + pair * 3;

        // geometry must stay f64: NCC amplifies x,y error by ~2/n2 (n2 ~ 7e-4 min)
        const double ka0 = Pp[0] * u + Pp[1] * v + Pp[2];
        const double ka1 = Pp[3] * u + Pp[4] * v + Pp[5];
        const double ka2 = Pp[6] * u + Pp[7] * v + Pp[8];
        const double p0 = depth * ka0 + ktp[0];
        const double p1 = depth * ka1 + ktp[1];
        const double p2 = depth * ka2 + ktp[2];

        const bool valid = p2 > 0.001;
        const double zs = fmax(p2, 0.001);
        const double invz = 1.0 / zs;
        const double x = p0 * invz;
        const double y = p1 * invz;

        const double x0f = floor(x);
        const double y0f = floor(y);
        const float fx = (float)(x - x0f);
        const float fy = (float)(y - y0f);
        const int x0 = (int)x0f;
        const int y0 = (int)y0f;
        const int y1 = y0 + 1;

        // x-pair weights: one 8B load at xa=clamp(x0,0,W-2); weights select
        // so wA*A + wB*B == w_x0*p[x0c] + w_x1*p[x1c] with OOB taps zeroed.
        const bool interior = (x0 >= 0) && (x0 < W - 1);
        const float wA = interior ? (1.0f - fx) : ((x0 == -1)    ? fx          : 0.0f);
        const float wB = interior ? fx          : ((x0 == W - 1) ? (1.0f - fx) : 0.0f);

        const bool oky0 = (y0 >= 0) && (y0 < H);
        const bool oky1 = (y1 >= 0) && (y1 < H);
        const float wy0 = (valid && oky0) ? (1.0f - fy) : 0.0f;
        const float wy1 = (valid && oky1) ? fy : 0.0f;

        // fold into 4 tap weights: bilinear = 4 FMA/channel
        const float w00 = wy0 * wA;
        const float w01 = wy0 * wB;
        const float w10 = wy1 * wA;
        const float w11 = wy1 * wB;

        const int xa  = min(max(x0, 0), W - 2);
        const int y0c = min(max(y0, 0), H - 1);
        const int y1c = min(max(y1, 0), H - 1);

        const float* base = src_feats + ((size_t)(s * B + b) * C) * HW;
        const float* pr0 = base + (y0c * W + xa);
        const float* pr1 = base + (y1c * W + xa);

        // pass 1: bilinear + sum + fused dot (dot = sum f1'*f2, de-biased after)
        float f2[C];
        float sum2 = 0.0f;
        float dot = 0.0f;
        #pragma unroll
        for (int c = 0; c < C; ++c) {
            const f32x2 r0 = load2(pr0);
            const f32x2 r1 = load2(pr1);
            const float val = fmaf(w00, r0.x, fmaf(w01, r0.y, fmaf(w10, r1.x, w11 * r1.y)));
            f2[c] = val;
            sum2 += val;
            dot = fmaf(f1[c], val, dot);
            pr0 += HW;
            pr1 += HW;
        }
        // pass 2: stable variance (explicit mean subtraction — do NOT use
        // sum(f2^2) - C*m2^2: catastrophic cancellation at low-variance pixels)
        const float m2 = sum2 * (1.0f / C);
        float sq2 = 0.0f;
        #pragma unroll
        for (int c = 0; c < C; ++c) {
            const float tv = f2[c] - m2;
            sq2 = fmaf(tv, tv, sq2);
        }
        dot = fmaf(-m2, sumf1p, dot);
        const float den = n1 * sqrtf(sq2) + 1e-6f;
        cost += dot / den;
    }

    out[idx] = cost * (1.0f / S);
}

// ---------------------------------------------------------------------------
// Fallback: round-3-style monolithic kernel (used only if ws too small)
// ---------------------------------------------------------------------------
__global__ __launch_bounds__(256) void plane_sweep_fallback(
    const float* __restrict__ ref_feats, const float* __restrict__ src_feats,
    const float* __restrict__ ref_intr, const float* __restrict__ src_intr,
    const float* __restrict__ ref_to_src, const float* __restrict__ depths,
    float* __restrict__ out)
{
    const int idx = blockIdx.x * blockDim.x + threadIdx.x;
    const int total = B * D * HW;
    if (idx >= total) return;
    const int w = idx % W;
    const int h = (idx / W) % H;
    const int d = (idx / HW) % D;
    const int b = idx / (HW * D);

    const float* Kp = ref_intr + b * 9;
    const double a00 = Kp[0], a01 = Kp[1], a02 = Kp[2];
    const double a10 = Kp[3], a11 = Kp[4], a12 = Kp[5];
    const double a20 = Kp[6], a21 = Kp[7], a22 = Kp[8];
    const double cof00 =  (a11 * a22 - a12 * a21);
    const double cof01 = -(a10 * a22 - a12 * a20);
    const double cof02 =  (a10 * a21 - a11 * a20);
    const double cof10 = -(a01 * a22 - a02 * a21);
    const double cof11 =  (a00 * a22 - a02 * a20);
    const double cof12 = -(a00 * a21 - a01 * a20);
    const double cof20 =  (a01 * a12 - a02 * a11);
    const double cof21 = -(a00 * a12 - a02 * a10);
    const double cof22 =  (a00 * a11 - a01 * a10);
    const double det = a00 * cof00 + a01 * cof01 + a02 * cof02;
    const double invdet = 1.0 / det;
    const double i00 = cof00 * invdet, i01 = cof10 * invdet, i02 = cof20 * invdet;
    const double i10 = cof01 * invdet, i11 = cof11 * invdet, i12 = cof21 * invdet;
    const double i20 = cof02 * invdet, i21 = cof12 * invdet, i22 = cof22 * invdet;
    const double u = (double)w, v = (double)h;
    const double rayx = i00 * u + i01 * v + i02;
    const double rayy = i10 * u + i11 * v + i12;
    const double rayz = i20 * u + i21 * v + i22;
    const double depth = (double)depths[d];
    const double X0 = depth * rayx, X1 = depth * rayy, X2 = depth * rayz;

    float f1[C];
    const float* rp = ref_feats + (b * C) * HW + h * W + w;
    float sum1 = 0.0f;
    #pragma unroll
    for (int c = 0; c < C; ++c) { f1[c] = rp[c * HW]; sum1 += f1[c]; }
    const float m1 = sum1 * (1.0f / C);
    float sq1 = 0.0f;
    #pragma unroll
    for (int c = 0; c < C; ++c) { f1[c] -= m1; sq1 += f1[c] * f1[c]; }
    const float n1 = sqrtf(sq1);

    float cost = 0.0f;
    for (int s = 0; s < S; ++s) {
        const float* Tp  = ref_to_src + (s * B + b) * 16;
        const float* Ksp = src_intr   + (s * B + b) * 9;
        const double Xsx = (double)Tp[0] * X0 + (double)Tp[1] * X1 + (double)Tp[2]  * X2 + (double)Tp[3];
        const double Xsy = (double)Tp[4] * X0 + (double)Tp[5] * X1 + (double)Tp[6]  * X2 + (double)Tp[7];
        const double Xsz = (double)Tp[8] * X0 + (double)Tp[9] * X1 + (double)Tp[10] * X2 + (double)Tp[11];
        const double p0 = (double)Ksp[0] * Xsx + (double)Ksp[1] * Xsy + (double)Ksp[2] * Xsz;
        const double p1 = (double)Ksp[3] * Xsx + (double)Ksp[4] * Xsy + (double)Ksp[5] * Xsz;
        const double p2 = (double)Ksp[6] * Xsx + (double)Ksp[7] * Xsy + (double)Ksp[8] * Xsz;
        const bool valid = p2 > 0.001;
        const double zs = fmax(p2, 0.001);
        const double invz = 1.0 / zs;
        const double x = p0 * invz, y = p1 * invz;
        const double x0f = floor(x), y0f = floor(y);
        const float fx = (float)(x - x0f), fy = (float)(y - y0f);
        const int x0 = (int)x0f, y0 = (int)y0f, y1 = y0 + 1;
        const bool interior = (x0 >= 0) && (x0 < W - 1);
        const float wA = interior ? (1.0f - fx) : ((x0 == -1)    ? fx          : 0.0f);
        const float wB = interior ? fx          : ((x0 == W - 1) ? (1.0f - fx) : 0.0f);
        const bool oky0 = (y0 >= 0) && (y0 < H);
        const bool oky1 = (y1 >= 0) && (y1 < H);
        const float wy0 = (valid && oky0) ? (1.0f - fy) : 0.0f;
        const float wy1 = (valid && oky1) ? fy : 0.0f;
        const int xa  = min(max(x0, 0), W - 2);
        const int y0c = min(max(y0, 0), H - 1);
        const int y1c = min(max(y1, 0), H - 1);
        const int off0 = y0c * W + xa, off1 = y1c * W + xa;
        const float* base = src_feats + ((size_t)(s * B + b) * C) * HW;
        float f2[C];
        float sum2 = 0.0f;
        #pragma unroll
        for (int c = 0; c < C; ++c) {
            const float* pc = base + c * HW;
            const f32x2 r0 = load2(pc + off0);
            const f32x2 r1 = load2(pc + off1);
            const float t0v = fmaf(wA, r0.x, wB * r0.y);
            const float t1v = fmaf(wA, r1.x, wB * r1.y);
            const float val = fmaf(wy0, t0v, wy1 * t1v);
            f2[c] = val; sum2 += val;
        }
        const float m2 = sum2 * (1.0f / C);
        float sq2 = 0.0f, dot = 0.0f;
        #pragma unroll
        for (int c = 0; c < C; ++c) {
            const float f2c = f2[c] - m2;
            sq2 = fmaf(f2c, f2c, sq2);
            dot = fmaf(f1[c], f2c, dot);
        }
        cost += dot / (n1 * sqrtf(sq2) + 1e-6f);
    }
    out[idx] = cost * (1.0f / S);
}

extern "C" void kernel_launch(void* const* d_in, const int* in_sizes, int n_in,
                              void* d_out, int out_size, void* d_ws, size_t ws_size,
                              hipStream_t stream) {
    const float* ref_feats  = (const float*)d_in[0];
    const float* src_feats  = (const float*)d_in[1];
    const float* ref_intr   = (const float*)d_in[2];
    const float* src_intr   = (const float*)d_in[3];
    const float* ref_to_src = (const float*)d_in[4];
    const float* depths     = (const float*)d_in[5];
    float* out = (float*)d_out;
    const int total = B * D * H * W;

    if (ws_size >= WS_NEEDED) {
        double* gp = (double*)d_ws;
        geom_small_kernel<<<1, 128, 0, stream>>>(ref_intr, src_intr, ref_to_src, gp);
        sweep_kernel<<<total / 256, 256, 0, stream>>>(
            ref_feats, src_feats, gp, depths, out);
    } else {
        plane_sweep_fallback<<<(total + 255) / 256, 256, 0, stream>>>(
            ref_feats, src_feats, ref_intr, src_intr, ref_to_src, depths, out);
    }
}